// Round 5
// baseline (306.715 us; speedup 1.0000x reference)
//
#include <hip/hip_runtime.h>

typedef unsigned short u16;
typedef unsigned long long u64;

// ---------------- problem constants ----------------
constexpr int cB = 4, cT = 40, cR = 2000, cA = 36864;
constexpr int cH = 64, cW = 64, cC = 256, cPP = 7;
constexpr int cNCLS = 21, cNPOS = 64, cNNEG = 192, cDH = 1024;
constexpr int cD = cPP * cPP * cC;          // 12544
constexpr int cBA = cB * cA;                // 147456
constexpr int cBR = cB * cR;                // 8000
constexpr int NW64 = cBA / 64;              // 2304 mask words
constexpr int SPLITS = 8;                   // k-splits for gemm1
constexpr int KCH = cD / SPLITS;            // 1568 = 49*32

// ---------------- ws layout (bytes), total ~15.9 MB ----------------
// Region 0 (0..8.39MB) triple duty, stream-ordered:
//   phase 1: tidx (cBA int) + maskw (2304 u64)     [k_rpn_iou -> k_rpn_sample_loss]
//   phase 2: fmt (B,HW,C) bf16 = 8388608 B          [k_fmt -> k_roi_pool]
//   phase 3: Cpart[8][256][1024] f32 = 8388608 B    [k_gemm1 -> k_bias_relu]
constexpr size_t O_TIDX  = 0;                                   // cBA int
constexpr size_t O_MASKW = (size_t)cBA * 4;                     // 2304 u64
constexpr size_t O_FMT   = 0;
constexpr size_t O_CPART = 0;
constexpr size_t O_PERS  = 8388608;
constexpr size_t O_SEL   = O_PERS;                              // 256 int
constexpr size_t O_CLS   = O_PERS + 1024;                       // 256 int
constexpr size_t O_ROIS  = O_PERS + 2048;                       // 256*4 f32
constexpr size_t O_TGT   = O_PERS + 6144;                       // 64*4 f32
constexpr size_t O_FEAT  = O_PERS + 8192;                       // 256*12544 bf16
constexpr size_t O_HMID  = O_FEAT + (size_t)256 * cD * 2;       // 256*1024 f32
constexpr size_t O_RREG  = O_HMID + (size_t)256 * cDH * 4;      // 256*4 f32
constexpr size_t O_RCLS  = O_RREG + 4096;                       // 256*21 f32

// ---------------- helpers ----------------
__device__ __forceinline__ float b2f(u16 u) {
  return __uint_as_float(((unsigned)u) << 16);
}
__device__ __forceinline__ u16 f2b(float f) {  // f32 -> bf16 bits (RNE)
  unsigned x = __float_as_uint(f);
  unsigned r = x + 0x7FFFu + ((x >> 16) & 1u);
  return (u16)(r >> 16);
}
__device__ __forceinline__ unsigned f2key(float f) {  // monotonic f32->u32
  unsigned b = __float_as_uint(f);
  return b ^ ((b & 0x80000000u) ? 0xFFFFFFFFu : 0x80000000u);
}

typedef __attribute__((ext_vector_type(8))) short short8;
typedef __attribute__((ext_vector_type(4))) float f32x4;

// ================= K1: RPN IoU / argmax per (b,a); mask as ballot words =====
__global__ void k_rpn_iou(const float* __restrict__ bboxes, const float* __restrict__ anchors,
                          int* __restrict__ tidx, u64* __restrict__ maskw) {
  __shared__ float sb[cT * 4];
  int b = blockIdx.x / 144;
  if (threadIdx.x < cT * 4) sb[threadIdx.x] = bboxes[b * cT * 4 + threadIdx.x];
  __syncthreads();
  int i = blockIdx.x * 256 + threadIdx.x;
  int a = i - b * cA;
  float4 av = ((const float4*)anchors)[a];
  float at = av.x, al = av.y, ab = av.z, ar = av.w;
  float area_a = (ab - at) * (ar - al);
  float best = -1.0f; int bi = 0;
  for (int t = 0; t < cT; ++t) {
    float bt = sb[t * 4], bl = sb[t * 4 + 1], bbv = sb[t * 4 + 2], brv = sb[t * 4 + 3];
    float ih = fmaxf(fminf(bbv, ab) - fmaxf(bt, at), 0.0f);
    float iw = fmaxf(fminf(brv, ar) - fmaxf(bl, al), 0.0f);
    float inter = ih * iw;
    float a1 = (bbv - bt) * (brv - bl);
    float iou = inter / (a1 + area_a - inter);
    if (iou > best) { best = iou; bi = t; }
  }
  tidx[i] = bi;
  u64 bal = __ballot(best > 0.5f);
  if ((threadIdx.x & 63) == 0) maskw[i >> 6] = bal;
}

// ================= K2: fused count + first-128/252 select + RPN losses ======
__global__ __launch_bounds__(1024) void k_rpn_sample_loss(
    const u64* __restrict__ maskw, const int* __restrict__ tidx,
    const float* __restrict__ rpn_cls, const float* __restrict__ rpn_reg,
    const float* __restrict__ bboxes, const float* __restrict__ anchors,
    float* __restrict__ out) {
  __shared__ u64 s_w[NW64];
  __shared__ int s_pre[144];
  __shared__ int s_cw[144];
  __shared__ int s_pos[128];
  __shared__ int s_neg[252];
  __shared__ float s_cls, s_reg;
  int tid = threadIdx.x, lane = tid & 63, w = tid >> 6;
  for (int k = tid; k < NW64; k += 1024) s_w[k] = maskw[k];
  if (tid < 128) s_pos[tid] = 0;
  if (tid < 252) s_neg[tid] = 0;
  if (tid == 0) { s_cls = 0.0f; s_reg = 0.0f; }
  __syncthreads();
  if (tid < 144) {
    int c = 0;
    #pragma unroll
    for (int k2 = 0; k2 < 16; ++k2) c += __popcll(s_w[tid * 16 + k2]);
    s_cw[tid] = c;
  }
  __syncthreads();
  if (tid == 0) {
    int run = 0;
    for (int ch = 0; ch < 144; ++ch) { s_pre[ch] = run; run += s_cw[ch]; }
  }
  __syncthreads();
  u64 lmask = (1ULL << lane) - 1ULL;
  for (int ch = w; ch < 144; ch += 16) {
    int pbase = s_pre[ch];
    int nbase = ch * 1024 - pbase;
    if (pbase >= 128 && nbase >= 252) continue;
    int pc = 0;
    #pragma unroll
    for (int s2 = 0; s2 < 16; ++s2) {
      u64 word = s_w[ch * 16 + s2];
      bool m = (word >> lane) & 1ULL;
      int prefP = __popcll(word & lmask);
      int idx = ch * 1024 + s2 * 64 + lane;
      if (m) {
        int g = pbase + pc + prefP;
        if (g < 128) s_pos[g] = idx;
      } else {
        int g = nbase + (s2 * 64 + lane) - (pc + prefP);
        if (g < 252) s_neg[g] = idx;
      }
      pc += __popcll(word);
    }
  }
  __syncthreads();
  if (tid < 380) {
    int flat; float lbl;
    if (tid < 128) { flat = s_pos[tid]; lbl = 1.0f; }
    else           { flat = s_neg[tid - 128]; lbl = 0.0f; }
    float l = rpn_cls[flat];
    float term = fmaxf(l, 0.0f) - l * lbl + log1pf(expf(-fabsf(l)));
    atomicAdd(&s_cls, term);
  }
  if (tid < 512) {
    int j = tid >> 2, c = tid & 3;
    int flat = s_pos[j];
    int b = flat / cA, a = flat - b * cA;
    int t = tidx[flat];
    float p = rpn_reg[flat * 4 + c];
    float tg = bboxes[(b * cT + t) * 4 + c] - anchors[a * 4 + c];
    float d = fabsf(p - tg);
    float sl = (d < 1.0f) ? 0.5f * d * d : d - 0.5f;
    atomicAdd(&s_reg, sl);
  }
  __syncthreads();
  if (tid == 0) {
    out[0] = s_cls / 380.0f;
    out[1] = s_reg / 512.0f / 4.0f;
  }
}

// ================= K3: fused RCNN IoU + selection (posr/top-192/rois/tgt) ===
__global__ __launch_bounds__(1024) void k_rcnn_all(
    const float* __restrict__ nms_reg, const float* __restrict__ bboxes,
    const int* __restrict__ classes,
    int* __restrict__ sel, int* __restrict__ cls_s,
    float* __restrict__ rois, float* __restrict__ tgt) {
  __shared__ float s_v[cBR];       // negscore (iou<=0.5 ? iou : -inf)
  __shared__ u16 s_ridx[cBR];
  __shared__ float s_bb[cB * cT * 4];
  __shared__ int s_wc[16];
  __shared__ int s_base;
  __shared__ int s_cnt;
  __shared__ int s_posr[64];
  __shared__ int s_negr[cNNEG];
  int tid = threadIdx.x, lane = tid & 63, w = tid >> 6;
  u64 lmask = (1ULL << lane) - 1ULL;

  for (int j = tid; j < cB * cT * 4; j += 1024) s_bb[j] = bboxes[j];
  if (tid < 64) s_posr[tid] = 0;
  if (tid < cNNEG) s_negr[tid] = 0;
  if (tid == 0) s_base = 0;
  __syncthreads();

  // ---- IoU argmax per roi ----
  #pragma unroll
  for (int r8 = 0; r8 < 8; ++r8) {
    int i = tid + r8 * 1024;
    if (i < cBR) {
      int b = i / cR;
      float4 nv = ((const float4*)nms_reg)[i];
      float nt = nv.x, nl = nv.y, nb = nv.z, nr = nv.w;
      float area_n = (nb - nt) * (nr - nl);
      float best = -1.0f; int bi = 0;
      for (int t = 0; t < cT; ++t) {
        const float* bx = &s_bb[(b * cT + t) * 4];
        float ih = fmaxf(fminf(bx[2], nb) - fmaxf(bx[0], nt), 0.0f);
        float iw = fmaxf(fminf(bx[3], nr) - fmaxf(bx[1], nl), 0.0f);
        float inter = ih * iw;
        float a1 = (bx[2] - bx[0]) * (bx[3] - bx[1]);
        float iou = inter / (a1 + area_n - inter);
        if (iou > best) { best = iou; bi = t; }
      }
      s_v[i] = (best <= 0.5f) ? best : -INFINITY;
      s_ridx[i] = (u16)bi;
    }
  }
  __syncthreads();

  // ---- posr: first 64 flat indices with iou > 0.5 (negscore == -inf) ----
  for (int base = 0; base < 8192; base += 1024) {
    int i = base + tid;
    bool v = (i < cBR) && (s_v[i] == -INFINITY);
    u64 bal = __ballot(v);
    int pref = __popcll(bal & lmask);
    if (lane == 0) s_wc[w] = __popcll(bal);
    __syncthreads();
    int off = 0, tot = 0;
    for (int w2 = 0; w2 < 16; ++w2) { if (w2 < w) off += s_wc[w2]; tot += s_wc[w2]; }
    int bs = s_base;
    if (v) { int g = bs + off + pref; if (g < 64) s_posr[g] = i; }
    __syncthreads();
    if (tid == 0) s_base = bs + tot;
    __syncthreads();
  }

  // ---- threshold for top-192 of negscore ----
  unsigned mykey[8];
  #pragma unroll
  for (int j = 0; j < 8; ++j) {
    int i = tid + j * 1024;
    mykey[j] = (i < cBR) ? f2key(s_v[i]) : 0u;
  }
  unsigned lo = 0, hi = 0xFFFFFFFFu;
  while (lo < hi) {
    unsigned mid = lo + ((hi - lo) >> 1) + 1u;
    __syncthreads();
    if (tid == 0) s_cnt = 0;
    __syncthreads();
    int c = 0;
    #pragma unroll
    for (int j = 0; j < 8; ++j) {
      int i = tid + j * 1024;
      if (i < cBR && mykey[j] >= mid) ++c;
    }
    for (int off = 32; off; off >>= 1) c += __shfl_down(c, off, 64);
    if (lane == 0) atomicAdd(&s_cnt, c);
    __syncthreads();
    unsigned cnt = (unsigned)s_cnt;
    if (cnt >= (unsigned)cNNEG) lo = mid; else hi = mid - 1u;
  }
  unsigned thr = lo;

  // ---- collect: strictly greater first, then ties by ascending index ----
  __syncthreads();
  if (tid == 0) s_base = 0;
  __syncthreads();
  for (int phase = 0; phase < 2; ++phase) {
    for (int base = 0; base < 8192; base += 1024) {
      int i = base + tid;
      bool v = false;
      if (i < cBR) {
        unsigned k = f2key(s_v[i]);
        v = phase ? (k == thr) : (k > thr);
      }
      u64 bal = __ballot(v);
      int pref = __popcll(bal & lmask);
      if (lane == 0) s_wc[w] = __popcll(bal);
      __syncthreads();
      int off = 0, tot = 0;
      for (int w2 = 0; w2 < 16; ++w2) { if (w2 < w) off += s_wc[w2]; tot += s_wc[w2]; }
      int bs = s_base;
      if (v) { int g = bs + off + pref; if (g < cNNEG) s_negr[g] = i; }
      __syncthreads();
      if (tid == 0) s_base = bs + tot;
      __syncthreads();
    }
  }
  __syncthreads();

  // ---- build sel, rois, cls_s, tgt ----
  if (tid < 256) {
    int flat = (tid < 64) ? s_posr[tid] : s_negr[tid - 64];
    sel[tid] = flat;
    int b = flat / cR;
    #pragma unroll
    for (int c = 0; c < 4; ++c) rois[tid * 4 + c] = nms_reg[flat * 4 + c];
    cls_s[tid] = (tid < 64) ? classes[b * cT + (int)s_ridx[flat]] : 0;
    if (tid < 64) {
      int mt = (int)s_ridx[flat];
      #pragma unroll
      for (int c = 0; c < 4; ++c) {
        float v = nms_reg[flat * 4 + c];
        float rr = ((c < 2) ? floorf(v * 16.0f) : ceilf(v * 16.0f)) / 16.0f;
        float mbv = s_bb[(b * cT + mt) * 4 + c];
        tgt[tid * 4 + c] = mbv - rr;
      }
    }
  }
}

// ================= K4: transpose fm (B,C,HW) f32 -> fmt (B,HW,C) bf16 =======
__global__ void k_fmt(const float* __restrict__ fm, u16* __restrict__ fmt) {
  __shared__ float tile[32][33];
  int b = blockIdx.z;
  int p0 = blockIdx.x * 32, c0 = blockIdx.y * 32;
  int tx = threadIdx.x, ty = threadIdx.y;
  tile[ty][tx] = fm[((size_t)b * cC + (c0 + ty)) * (cH * cW) + p0 + tx];
  __syncthreads();
  fmt[((size_t)b * (cH * cW) + (p0 + ty)) * cC + c0 + tx] = f2b(tile[tx][ty]);
}

// ================= K5: ROI align (coalesced, one block per roi x bin-row) ===
__global__ void k_roi_pool(const u16* __restrict__ fmt, const float* __restrict__ rois,
                           const int* __restrict__ sel, u16* __restrict__ feat) {
  int j = blockIdx.x;    // roi
  int py = blockIdx.y;   // bin row 0..6
  int c = threadIdx.x;   // channel
  int flat = sel[j];
  int n = flat / cR;
  float t = rois[j * 4 + 0], l = rois[j * 4 + 1];
  float bb = rois[j * 4 + 2], r = rois[j * 4 + 3];
  const u16* base = fmt + (size_t)n * (cH * cW) * cC;
  float gy = (py + 0.5f) / (float)cPP;
  float ys = fminf(fmaxf(t + gy * (bb - t), 0.0f), 63.0f);
  int y0 = (int)floorf(ys);
  int y1 = min(y0 + 1, 63);
  float wy = ys - (float)y0;
  #pragma unroll
  for (int px = 0; px < cPP; ++px) {
    float gx = (px + 0.5f) / (float)cPP;
    float xs = fminf(fmaxf(l + gx * (r - l), 0.0f), 63.0f);
    int x0 = (int)floorf(xs);
    int x1 = min(x0 + 1, 63);
    float wx = xs - (float)x0;
    float f00 = b2f(base[(y0 * cW + x0) * cC + c]);
    float f01 = b2f(base[(y0 * cW + x1) * cC + c]);
    float f10 = b2f(base[(y1 * cW + x0) * cC + c]);
    float f11 = b2f(base[(y1 * cW + x1) * cC + c]);
    float v = f00 * (1.0f - wy) * (1.0f - wx) + f01 * (1.0f - wy) * wx +
              f10 * wy * (1.0f - wx) + f11 * wy * wx;
    feat[((size_t)j * 49 + py * cPP + px) * cC + c] = f2b(v);
  }
}

// ================= K6: GEMM1 feat(256x12544 bf16) @ W1(12544x1024 f32) ======
// Grid (16 n, 8 ksplit, 2 mhalf) = 256 blocks. Register-prefetch pipeline,
// plain stores to Cpart[ks] (reduced in k_bias_relu). LDS stride 56 u16:
// 16B-aligned ds_read_b128, 2-way bank pattern (free).
__global__ __launch_bounds__(256) void k_gemm1(const u16* __restrict__ feat, const float* __restrict__ W1,
                                               float* __restrict__ Cpart) {
  __shared__ u16 As[128][56];
  __shared__ u16 Bs[64][56];
  int tid = threadIdx.x;
  int n0 = blockIdx.x * 64;
  int kb0 = blockIdx.y * KCH;
  int m0 = blockIdx.z * 128;
  int lane = tid & 63, w = tid >> 6;
  int r = lane & 15, q = lane >> 4;
  f32x4 acc[2][4] = {};
  int arow = tid >> 1, ak = (tid & 1) * 16;     // A: 128 rows x 32 k, 32B/thread
  int bk = tid >> 3, bn = (tid & 7) * 8;        // B: 32 k x 64 n, 8 f32/thread
  uint4 ra0, ra1;
  float4 rb0, rb1;
  {
    const u16* ap = &feat[(size_t)(m0 + arow) * cD + kb0 + ak];
    ra0 = *(const uint4*)ap; ra1 = *(const uint4*)(ap + 8);
    const float* bp = &W1[(size_t)(kb0 + bk) * cDH + n0 + bn];
    rb0 = *(const float4*)bp; rb1 = *(const float4*)(bp + 4);
  }
  for (int kc = 0; kc < KCH / 32; ++kc) {
    __syncthreads();
    *(uint4*)&As[arow][ak] = ra0;
    *(uint4*)&As[arow][ak + 8] = ra1;
    Bs[bn + 0][bk] = f2b(rb0.x); Bs[bn + 1][bk] = f2b(rb0.y);
    Bs[bn + 2][bk] = f2b(rb0.z); Bs[bn + 3][bk] = f2b(rb0.w);
    Bs[bn + 4][bk] = f2b(rb1.x); Bs[bn + 5][bk] = f2b(rb1.y);
    Bs[bn + 6][bk] = f2b(rb1.z); Bs[bn + 7][bk] = f2b(rb1.w);
    if (kc + 1 < KCH / 32) {
      int kb = kb0 + (kc + 1) * 32;
      const u16* ap = &feat[(size_t)(m0 + arow) * cD + kb + ak];
      ra0 = *(const uint4*)ap; ra1 = *(const uint4*)(ap + 8);
      const float* bp = &W1[(size_t)(kb + bk) * cDH + n0 + bn];
      rb0 = *(const float4*)bp; rb1 = *(const float4*)(bp + 4);
    }
    __syncthreads();
    short8 a[2], bfr[4];
    #pragma unroll
    for (int mt = 0; mt < 2; ++mt) a[mt] = *(const short8*)&As[w * 32 + mt * 16 + r][q * 8];
    #pragma unroll
    for (int nt = 0; nt < 4; ++nt) bfr[nt] = *(const short8*)&Bs[nt * 16 + r][q * 8];
    #pragma unroll
    for (int mt = 0; mt < 2; ++mt)
      #pragma unroll
      for (int nt = 0; nt < 4; ++nt)
        acc[mt][nt] = __builtin_amdgcn_mfma_f32_16x16x32_bf16(a[mt], bfr[nt], acc[mt][nt], 0, 0, 0);
  }
  float* Cp = Cpart + (size_t)blockIdx.y * 256 * cDH;
  #pragma unroll
  for (int mt = 0; mt < 2; ++mt) {
    #pragma unroll
    for (int nt = 0; nt < 4; ++nt) {
      #pragma unroll
      for (int rg = 0; rg < 4; ++rg) {
        int row = m0 + w * 32 + mt * 16 + q * 4 + rg;
        int col = n0 + nt * 16 + r;
        Cp[(size_t)row * cDH + col] = acc[mt][nt][rg];
      }
    }
  }
}

// ================= K7: reduce split-K + bias + relu -> hmid (f32) ===========
__global__ void k_bias_relu(const float* __restrict__ Cpart, const float* __restrict__ b1,
                            float* __restrict__ hmid) {
  int i = blockIdx.x * 256 + threadIdx.x;
  float v = b1[i & (cDH - 1)];
  #pragma unroll
  for (int s = 0; s < SPLITS; ++s) v += Cpart[(size_t)s * 256 * cDH + i];
  hmid[i] = fmaxf(v, 0.0f);
}

// ================= K8: heads rreg/rcls =================
__global__ void k_gemm2(const float* __restrict__ hmid, const float* __restrict__ Wr, const float* __restrict__ br,
                        const float* __restrict__ Wc, const float* __restrict__ bc,
                        float* __restrict__ rreg, float* __restrict__ rcls) {
  int w = threadIdx.x >> 6, lane = threadIdx.x & 63;
  int row = blockIdx.x * 4 + w;
  float part[25];
  #pragma unroll
  for (int c = 0; c < 25; ++c) part[c] = 0.0f;
  for (int k = lane; k < cDH; k += 64) {
    float h = hmid[(size_t)row * cDH + k];
    #pragma unroll
    for (int c = 0; c < 4; ++c) part[c] += h * Wr[k * 4 + c];
    #pragma unroll
    for (int c = 0; c < 21; ++c) part[4 + c] += h * Wc[k * 21 + c];
  }
  #pragma unroll
  for (int off = 32; off; off >>= 1) {
    #pragma unroll
    for (int c = 0; c < 25; ++c) part[c] += __shfl_down(part[c], off, 64);
  }
  if (lane == 0) {
    #pragma unroll
    for (int c = 0; c < 4; ++c) rreg[row * 4 + c] = part[c] + br[c];
    #pragma unroll
    for (int c = 0; c < 21; ++c) rcls[row * 21 + c] = part[4 + c] + bc[c];
  }
}

// ================= K9: final losses =================
__global__ void k_final(const float* __restrict__ rcls, const float* __restrict__ rreg,
                        const int* __restrict__ cls_s, const float* __restrict__ tgt,
                        float* __restrict__ out) {
  __shared__ float s_cls, s_acc, s_sl1, s_off;
  int tid = threadIdx.x;
  if (tid == 0) { s_cls = 0.0f; s_acc = 0.0f; s_sl1 = 0.0f; s_off = 0.0f; }
  __syncthreads();
  {
    int row = tid;
    float m = -INFINITY;
    for (int c = 0; c < cNCLS; ++c) m = fmaxf(m, rcls[row * cNCLS + c]);
    float sum = 0.0f;
    for (int c = 0; c < cNCLS; ++c) sum += expf(rcls[row * cNCLS + c] - m);
    float lse = m + logf(sum);
    float closs = lse - rcls[row * cNCLS + cls_s[row]];
    atomicAdd(&s_cls, closs);
  }
  if (tid < 64) {
    int am = 0; float bv = rcls[tid * cNCLS];
    for (int c = 1; c < cNCLS; ++c) {
      float v = rcls[tid * cNCLS + c];
      if (v > bv) { bv = v; am = c; }
    }
    if (am == cls_s[tid]) atomicAdd(&s_acc, 1.0f);
    float sl = 0.0f, of = 0.0f;
    #pragma unroll
    for (int c = 0; c < 4; ++c) {
      float d = fabsf(rreg[tid * 4 + c] - tgt[tid * 4 + c]);
      sl += (d < 1.0f) ? 0.5f * d * d : d - 0.5f;
      of += d;
    }
    atomicAdd(&s_sl1, sl);
    atomicAdd(&s_off, of);
  }
  __syncthreads();
  if (tid == 0) {
    out[2] = s_cls / 256.0f;
    out[3] = s_sl1 / 256.0f;
    out[4] = s_acc / 64.0f;
    out[5] = s_off / 256.0f;
  }
}

// ================= launch =================
extern "C" void kernel_launch(void* const* d_in, const int* in_sizes, int n_in,
                              void* d_out, int out_size, void* d_ws, size_t ws_size,
                              hipStream_t stream) {
  const float* nms_reg = (const float*)d_in[0];
  // d_in[1] (nms_cls) unused by the reference loss
  const float* fm      = (const float*)d_in[2];
  const float* bboxes  = (const float*)d_in[3];
  const int*   classes = (const int*)d_in[4];
  const float* anchors = (const float*)d_in[5];
  const float* rpn_reg = (const float*)d_in[6];
  const float* rpn_cls = (const float*)d_in[7];
  const float* W1      = (const float*)d_in[8];
  const float* b1      = (const float*)d_in[9];
  const float* Wr      = (const float*)d_in[10];
  const float* br      = (const float*)d_in[11];
  const float* Wc      = (const float*)d_in[12];
  const float* bc      = (const float*)d_in[13];
  float* out = (float*)d_out;
  char* ws = (char*)d_ws;

  int*   tidx  = (int*)(ws + O_TIDX);
  u64*   maskw = (u64*)(ws + O_MASKW);
  u16*   fmt   = (u16*)(ws + O_FMT);    // phase-2 alias
  float* Cpart = (float*)(ws + O_CPART); // phase-3 alias
  int*   sel   = (int*)(ws + O_SEL);
  int*   clss  = (int*)(ws + O_CLS);
  float* rois  = (float*)(ws + O_ROIS);
  float* tgt   = (float*)(ws + O_TGT);
  u16*   feat  = (u16*)(ws + O_FEAT);
  float* hmid  = (float*)(ws + O_HMID);
  float* rreg  = (float*)(ws + O_RREG);
  float* rcls  = (float*)(ws + O_RCLS);

  // RPN branch
  k_rpn_iou<<<cBA / 256, 256, 0, stream>>>(bboxes, anchors, tidx, maskw);
  k_rpn_sample_loss<<<1, 1024, 0, stream>>>(maskw, tidx, rpn_cls, rpn_reg, bboxes, anchors, out);

  // RCNN sampling (fused)
  k_rcnn_all<<<1, 1024, 0, stream>>>(nms_reg, bboxes, classes, sel, clss, rois, tgt);

  // Features + head
  k_fmt<<<dim3(cH * cW / 32, cC / 32, cB), dim3(32, 32), 0, stream>>>(fm, fmt);
  k_roi_pool<<<dim3(256, cPP), 256, 0, stream>>>(fmt, rois, sel, feat);
  k_gemm1<<<dim3(16, SPLITS, 2), 256, 0, stream>>>(feat, W1, Cpart);
  k_bias_relu<<<(256 * cDH) / 256, 256, 0, stream>>>(Cpart, b1, hmid);
  k_gemm2<<<64, 256, 0, stream>>>(hmid, Wr, br, Wc, bc, rreg, rcls);
  k_final<<<1, 256, 0, stream>>>(rcls, rreg, clss, tgt, out);
}

// Round 6
// 226.443 us; speedup vs baseline: 1.3545x; 1.3545x over previous
//
#include <hip/hip_runtime.h>

typedef unsigned short u16;
typedef unsigned long long u64;

// ---------------- problem constants ----------------
constexpr int cB = 4, cT = 40, cR = 2000, cA = 36864;
constexpr int cH = 64, cW = 64, cC = 256, cPP = 7;
constexpr int cNCLS = 21, cNPOS = 64, cNNEG = 192, cDH = 1024;
constexpr int cD = cPP * cPP * cC;          // 12544
constexpr int cBA = cB * cA;                // 147456
constexpr int cBR = cB * cR;                // 8000
constexpr int NW64 = cBA / 64;              // 2304 mask words
constexpr int SPLITS = 8;                   // k-splits for gemm1
constexpr int KCH = cD / SPLITS;            // 1568 = 49*32
constexpr unsigned POSKEY = 0x007FFFFFu;    // f2key(-inf): marks iou>0.5

// ---------------- ws layout (bytes), total ~16.0 MB ----------------
constexpr size_t O_TIDX  = 0;                                   // cBA int
constexpr size_t O_MASKW = (size_t)cBA * 4;                     // 2304 u64
constexpr size_t O_FMT   = 0;                                   // phase-2 alias
constexpr size_t O_CPART = 0;                                   // phase-3 alias
constexpr size_t O_PERS  = 8388608;
constexpr size_t O_SEL   = O_PERS;                              // 256 int
constexpr size_t O_CLS   = O_PERS + 1024;                       // 256 int
constexpr size_t O_ROIS  = O_PERS + 2048;                       // 256*4 f32
constexpr size_t O_TGT   = O_PERS + 6144;                       // 64*4 f32
constexpr size_t O_FEAT  = O_PERS + 8192;                       // 256*12544 bf16
constexpr size_t O_HMID  = O_FEAT + (size_t)256 * cD * 2;       // 256*1024 f32
constexpr size_t O_RREG  = O_HMID + (size_t)256 * cDH * 4;      // 256*4 f32
constexpr size_t O_RCLS  = O_RREG + 4096;                       // 256*21 f32
constexpr size_t O_KEYS  = O_RCLS + 24576;                      // 8000 u32
constexpr size_t O_RIDXG = O_KEYS + 32000;                      // 8000 int

// ---------------- helpers ----------------
__device__ __forceinline__ float b2f(u16 u) {
  return __uint_as_float(((unsigned)u) << 16);
}
__device__ __forceinline__ u16 f2b(float f) {  // f32 -> bf16 bits (RNE)
  unsigned x = __float_as_uint(f);
  unsigned r = x + 0x7FFFu + ((x >> 16) & 1u);
  return (u16)(r >> 16);
}
__device__ __forceinline__ unsigned f2key(float f) {  // monotonic f32->u32
  unsigned b = __float_as_uint(f);
  return b ^ ((b & 0x80000000u) ? 0xFFFFFFFFu : 0x80000000u);
}

typedef __attribute__((ext_vector_type(8))) short short8;
typedef __attribute__((ext_vector_type(4))) float f32x4;

// ================= K1: RPN IoU / argmax per (b,a); mask as ballot words =====
__global__ void k_rpn_iou(const float* __restrict__ bboxes, const float* __restrict__ anchors,
                          int* __restrict__ tidx, u64* __restrict__ maskw) {
  __shared__ float sb[cT * 4];
  int b = blockIdx.x / 144;
  if (threadIdx.x < cT * 4) sb[threadIdx.x] = bboxes[b * cT * 4 + threadIdx.x];
  __syncthreads();
  int i = blockIdx.x * 256 + threadIdx.x;
  int a = i - b * cA;
  float4 av = ((const float4*)anchors)[a];
  float at = av.x, al = av.y, ab = av.z, ar = av.w;
  float area_a = (ab - at) * (ar - al);
  float best = -1.0f; int bi = 0;
  for (int t = 0; t < cT; ++t) {
    float bt = sb[t * 4], bl = sb[t * 4 + 1], bbv = sb[t * 4 + 2], brv = sb[t * 4 + 3];
    float ih = fmaxf(fminf(bbv, ab) - fmaxf(bt, at), 0.0f);
    float iw = fmaxf(fminf(brv, ar) - fmaxf(bl, al), 0.0f);
    float inter = ih * iw;
    float a1 = (bbv - bt) * (brv - bl);
    float iou = inter / (a1 + area_a - inter);
    if (iou > best) { best = iou; bi = t; }
  }
  tidx[i] = bi;
  u64 bal = __ballot(best > 0.5f);
  if ((threadIdx.x & 63) == 0) maskw[i >> 6] = bal;
}

// ================= K2: fused count + first-128/252 select + RPN losses ======
__global__ __launch_bounds__(1024) void k_rpn_sample_loss(
    const u64* __restrict__ maskw, const int* __restrict__ tidx,
    const float* __restrict__ rpn_cls, const float* __restrict__ rpn_reg,
    const float* __restrict__ bboxes, const float* __restrict__ anchors,
    float* __restrict__ out) {
  __shared__ u64 s_w[NW64];
  __shared__ int s_pre[144];
  __shared__ int s_cw[144];
  __shared__ int s_pos[128];
  __shared__ int s_neg[252];
  __shared__ float s_cls, s_reg;
  int tid = threadIdx.x, lane = tid & 63, w = tid >> 6;
  for (int k = tid; k < NW64; k += 1024) s_w[k] = maskw[k];
  if (tid < 128) s_pos[tid] = 0;
  if (tid < 252) s_neg[tid] = 0;
  if (tid == 0) { s_cls = 0.0f; s_reg = 0.0f; }
  __syncthreads();
  if (tid < 144) {
    int c = 0;
    #pragma unroll
    for (int k2 = 0; k2 < 16; ++k2) c += __popcll(s_w[tid * 16 + k2]);
    s_cw[tid] = c;
  }
  __syncthreads();
  if (tid == 0) {
    int run = 0;
    for (int ch = 0; ch < 144; ++ch) { s_pre[ch] = run; run += s_cw[ch]; }
  }
  __syncthreads();
  u64 lmask = (1ULL << lane) - 1ULL;
  for (int ch = w; ch < 144; ch += 16) {
    int pbase = s_pre[ch];
    int nbase = ch * 1024 - pbase;
    if (pbase >= 128 && nbase >= 252) continue;
    int pc = 0;
    #pragma unroll
    for (int s2 = 0; s2 < 16; ++s2) {
      u64 word = s_w[ch * 16 + s2];
      bool m = (word >> lane) & 1ULL;
      int prefP = __popcll(word & lmask);
      int idx = ch * 1024 + s2 * 64 + lane;
      if (m) {
        int g = pbase + pc + prefP;
        if (g < 128) s_pos[g] = idx;
      } else {
        int g = nbase + (s2 * 64 + lane) - (pc + prefP);
        if (g < 252) s_neg[g] = idx;
      }
      pc += __popcll(word);
    }
  }
  __syncthreads();
  if (tid < 380) {
    int flat; float lbl;
    if (tid < 128) { flat = s_pos[tid]; lbl = 1.0f; }
    else           { flat = s_neg[tid - 128]; lbl = 0.0f; }
    float l = rpn_cls[flat];
    float term = fmaxf(l, 0.0f) - l * lbl + log1pf(expf(-fabsf(l)));
    atomicAdd(&s_cls, term);
  }
  if (tid < 512) {
    int j = tid >> 2, c = tid & 3;
    int flat = s_pos[j];
    int b = flat / cA, a = flat - b * cA;
    int t = tidx[flat];
    float p = rpn_reg[flat * 4 + c];
    float tg = bboxes[(b * cT + t) * 4 + c] - anchors[a * 4 + c];
    float d = fabsf(p - tg);
    float sl = (d < 1.0f) ? 0.5f * d * d : d - 0.5f;
    atomicAdd(&s_reg, sl);
  }
  __syncthreads();
  if (tid == 0) {
    out[0] = s_cls / 380.0f;
    out[1] = s_reg / 512.0f / 4.0f;
  }
}

// ================= K3a: RCNN IoU (grid) -> keys + ridx ======================
__global__ void k_rcnn_iou(const float* __restrict__ nms_reg, const float* __restrict__ bboxes,
                           unsigned* __restrict__ keys, int* __restrict__ ridx) {
  __shared__ float sb[cB * cT * 4];
  for (int j = threadIdx.x; j < cB * cT * 4; j += 256) sb[j] = bboxes[j];
  __syncthreads();
  int i = blockIdx.x * 256 + threadIdx.x;
  if (i >= cBR) return;
  int b = i / cR;
  float4 nv = ((const float4*)nms_reg)[i];
  float nt = nv.x, nl = nv.y, nb = nv.z, nr = nv.w;
  float area_n = (nb - nt) * (nr - nl);
  float best = -1.0f; int bi = 0;
  for (int t = 0; t < cT; ++t) {
    const float* bx = &sb[(b * cT + t) * 4];
    float ih = fmaxf(fminf(bx[2], nb) - fmaxf(bx[0], nt), 0.0f);
    float iw = fmaxf(fminf(bx[3], nr) - fmaxf(bx[1], nl), 0.0f);
    float inter = ih * iw;
    float a1 = (bx[2] - bx[0]) * (bx[3] - bx[1]);
    float iou = inter / (a1 + area_n - inter);
    if (iou > best) { best = iou; bi = t; }
  }
  keys[i] = (best <= 0.5f) ? f2key(best) : POSKEY;
  ridx[i] = bi;
}

// ================= K3b: selection — radix-histogram top-192 + posr ==========
__global__ __launch_bounds__(1024) void k_rcnn_select(
    const unsigned* __restrict__ keysg, const int* __restrict__ ridxg,
    const float* __restrict__ nms_reg, const float* __restrict__ bboxes,
    const int* __restrict__ classes,
    int* __restrict__ sel, int* __restrict__ cls_s,
    float* __restrict__ rois, float* __restrict__ tgt) {
  __shared__ unsigned s_key[cBR];
  __shared__ int s_hist[4096];
  __shared__ int s_pc[128];
  __shared__ int s_wsum[16], s_wsuf[16];
  __shared__ int s_posr[64], s_negr[cNNEG];
  __shared__ int s_bStar, s_over, s_cnt;
  int tid = threadIdx.x, lane = tid & 63, w = tid >> 6;
  u64 lmask = (1ULL << lane) - 1ULL;

  for (int i = tid; i < cBR; i += 1024) s_key[i] = keysg[i];
  if (tid < 64) s_posr[tid] = 0;
  __syncthreads();

  // ---- posr: first 64 flat indices with key==POSKEY (2-barrier rank fill) --
  {
    int myv = 0; int mypre[8];
    #pragma unroll
    for (int p = 0; p < 8; ++p) {
      int i = p * 1024 + tid;
      bool v = (i < cBR) && (s_key[i] == POSKEY);
      u64 bal = __ballot(v);
      if (lane == 0) s_pc[p * 16 + w] = __popcll(bal);
      mypre[p] = __popcll(bal & lmask);
      myv |= v ? (1 << p) : 0;
    }
    __syncthreads();
    if (tid == 0) {
      int run = 0;
      for (int k = 0; k < 128; ++k) { int t = s_pc[k]; s_pc[k] = run; run += t; }
    }
    __syncthreads();
    #pragma unroll
    for (int p = 0; p < 8; ++p) {
      if (myv & (1 << p)) {
        int g = s_pc[p * 16 + w] + mypre[p];
        if (g < 64) s_posr[g] = p * 1024 + tid;
      }
    }
  }

  // ---- 3-level radix threshold: exact 192nd-largest key ----
  unsigned thr = 0; int G = 0;  // computed below (uniform)
  int need = cNNEG;
  #pragma unroll
  for (int lvl = 0; lvl < 3; ++lvl) {
    __syncthreads();
    #pragma unroll
    for (int k = 0; k < 4; ++k) s_hist[tid * 4 + k] = 0;
    __syncthreads();
    #pragma unroll
    for (int p = 0; p < 8; ++p) {
      int i = p * 1024 + tid;
      if (i < cBR) {
        unsigned key = s_key[i];
        int bkt = -1;
        if (lvl == 0) bkt = key >> 20;
        else if (lvl == 1) { if ((key >> 20) == (thr >> 20)) bkt = (key >> 8) & 0xFFF; }
        else { if ((key >> 8) == (thr >> 8)) bkt = (key & 0xFF) << 4; }  // spread 256 into 4096
        if (bkt >= 0) atomicAdd(&s_hist[bkt], 1);
      }
    }
    __syncthreads();
    // parallel suffix scan over 4096 buckets; find b*: S(b*)>=need, S(b*+1)<need
    int local0 = s_hist[tid * 4 + 0], local1 = s_hist[tid * 4 + 1];
    int local2 = s_hist[tid * 4 + 2], local3 = s_hist[tid * 4 + 3];
    int lsum = local0 + local1 + local2 + local3;
    int x = lsum;
    #pragma unroll
    for (int off = 1; off < 64; off <<= 1) {
      int t = __shfl_down(x, off, 64);
      if (lane + off < 64) x += t;
    }
    if (lane == 0) s_wsum[w] = x;
    __syncthreads();
    if (tid == 0) {
      int run = 0;
      for (int wi = 15; wi >= 0; --wi) { s_wsuf[wi] = run; run += s_wsum[wi]; }
    }
    __syncthreads();
    int above = s_wsuf[w] + (x - lsum);  // keys in buckets > my group
    int run = above;
    int loc[4] = {local3, local2, local1, local0};
    #pragma unroll
    for (int j = 0; j < 4; ++j) {   // buckets 4t+3 down to 4t
      int S = run + loc[j];
      if (run < need && S >= need) { s_bStar = tid * 4 + (3 - j); s_over = run; }
      run = S;
    }
    __syncthreads();
    int bS = s_bStar, ov = s_over;
    if (lvl == 0) thr = ((unsigned)bS) << 20;
    else if (lvl == 1) thr |= ((unsigned)bS) << 8;
    else thr |= ((unsigned)bS) >> 4;
    G += ov;
    need -= ov;
  }
  // G = # keys strictly > thr; need = ties to take (by ascending index)

  // ---- negr: unordered collect of strictly-greater ----
  if (tid == 0) s_cnt = 0;
  __syncthreads();
  #pragma unroll
  for (int p = 0; p < 8; ++p) {
    int i = p * 1024 + tid;
    if (i < cBR && s_key[i] > thr) {
      int slot = atomicAdd(&s_cnt, 1);
      s_negr[slot] = i;
    }
  }
  // ---- ties: first `need` with key==thr, ascending index (2-barrier fill) --
  {
    __syncthreads();
    int myv = 0; int mypre[8];
    #pragma unroll
    for (int p = 0; p < 8; ++p) {
      int i = p * 1024 + tid;
      bool v = (i < cBR) && (s_key[i] == thr);
      u64 bal = __ballot(v);
      if (lane == 0) s_pc[p * 16 + w] = __popcll(bal);
      mypre[p] = __popcll(bal & lmask);
      myv |= v ? (1 << p) : 0;
    }
    __syncthreads();
    if (tid == 0) {
      int run = 0;
      for (int k = 0; k < 128; ++k) { int t = s_pc[k]; s_pc[k] = run; run += t; }
    }
    __syncthreads();
    #pragma unroll
    for (int p = 0; p < 8; ++p) {
      if (myv & (1 << p)) {
        int g = s_pc[p * 16 + w] + mypre[p];
        if (g < need) s_negr[G + g] = p * 1024 + tid;
      }
    }
  }
  __syncthreads();

  // ---- build sel, rois, cls_s, tgt ----
  if (tid < 256) {
    int flat = (tid < 64) ? s_posr[tid] : s_negr[tid - 64];
    sel[tid] = flat;
    int b = flat / cR;
    #pragma unroll
    for (int c = 0; c < 4; ++c) rois[tid * 4 + c] = nms_reg[flat * 4 + c];
    cls_s[tid] = (tid < 64) ? classes[b * cT + ridxg[flat]] : 0;
    if (tid < 64) {
      int mt = ridxg[flat];
      #pragma unroll
      for (int c = 0; c < 4; ++c) {
        float v = nms_reg[flat * 4 + c];
        float rr = ((c < 2) ? floorf(v * 16.0f) : ceilf(v * 16.0f)) / 16.0f;
        float mbv = bboxes[(b * cT + mt) * 4 + c];
        tgt[tid * 4 + c] = mbv - rr;
      }
    }
  }
}

// ================= K4: transpose fm (B,C,HW) f32 -> fmt (B,HW,C) bf16 =======
__global__ void k_fmt(const float* __restrict__ fm, u16* __restrict__ fmt) {
  __shared__ float tile[32][33];
  int b = blockIdx.z;
  int p0 = blockIdx.x * 32, c0 = blockIdx.y * 32;
  int tx = threadIdx.x, ty = threadIdx.y;
  tile[ty][tx] = fm[((size_t)b * cC + (c0 + ty)) * (cH * cW) + p0 + tx];
  __syncthreads();
  fmt[((size_t)b * (cH * cW) + (p0 + ty)) * cC + c0 + tx] = f2b(tile[tx][ty]);
}

// ================= K5: ROI align (coalesced, one block per roi x bin-row) ===
__global__ void k_roi_pool(const u16* __restrict__ fmt, const float* __restrict__ rois,
                           const int* __restrict__ sel, u16* __restrict__ feat) {
  int j = blockIdx.x;    // roi
  int py = blockIdx.y;   // bin row 0..6
  int c = threadIdx.x;   // channel
  int flat = sel[j];
  int n = flat / cR;
  float t = rois[j * 4 + 0], l = rois[j * 4 + 1];
  float bb = rois[j * 4 + 2], r = rois[j * 4 + 3];
  const u16* base = fmt + (size_t)n * (cH * cW) * cC;
  float gy = (py + 0.5f) / (float)cPP;
  float ys = fminf(fmaxf(t + gy * (bb - t), 0.0f), 63.0f);
  int y0 = (int)floorf(ys);
  int y1 = min(y0 + 1, 63);
  float wy = ys - (float)y0;
  #pragma unroll
  for (int px = 0; px < cPP; ++px) {
    float gx = (px + 0.5f) / (float)cPP;
    float xs = fminf(fmaxf(l + gx * (r - l), 0.0f), 63.0f);
    int x0 = (int)floorf(xs);
    int x1 = min(x0 + 1, 63);
    float wx = xs - (float)x0;
    float f00 = b2f(base[(y0 * cW + x0) * cC + c]);
    float f01 = b2f(base[(y0 * cW + x1) * cC + c]);
    float f10 = b2f(base[(y1 * cW + x0) * cC + c]);
    float f11 = b2f(base[(y1 * cW + x1) * cC + c]);
    float v = f00 * (1.0f - wy) * (1.0f - wx) + f01 * (1.0f - wy) * wx +
              f10 * wy * (1.0f - wx) + f11 * wy * wx;
    feat[((size_t)j * 49 + py * cPP + px) * cC + c] = f2b(v);
  }
}

// ================= K6: GEMM1 feat(256x12544 bf16) @ W1(12544x1024 f32) ======
__global__ __launch_bounds__(256) void k_gemm1(const u16* __restrict__ feat, const float* __restrict__ W1,
                                               float* __restrict__ Cpart) {
  __shared__ u16 As[128][56];
  __shared__ u16 Bs[64][56];
  int tid = threadIdx.x;
  int n0 = blockIdx.x * 64;
  int kb0 = blockIdx.y * KCH;
  int m0 = blockIdx.z * 128;
  int lane = tid & 63, w = tid >> 6;
  int r = lane & 15, q = lane >> 4;
  f32x4 acc[2][4] = {};
  int arow = tid >> 1, ak = (tid & 1) * 16;
  int bk = tid >> 3, bn = (tid & 7) * 8;
  uint4 ra0, ra1;
  float4 rb0, rb1;
  {
    const u16* ap = &feat[(size_t)(m0 + arow) * cD + kb0 + ak];
    ra0 = *(const uint4*)ap; ra1 = *(const uint4*)(ap + 8);
    const float* bp = &W1[(size_t)(kb0 + bk) * cDH + n0 + bn];
    rb0 = *(const float4*)bp; rb1 = *(const float4*)(bp + 4);
  }
  for (int kc = 0; kc < KCH / 32; ++kc) {
    __syncthreads();
    *(uint4*)&As[arow][ak] = ra0;
    *(uint4*)&As[arow][ak + 8] = ra1;
    Bs[bn + 0][bk] = f2b(rb0.x); Bs[bn + 1][bk] = f2b(rb0.y);
    Bs[bn + 2][bk] = f2b(rb0.z); Bs[bn + 3][bk] = f2b(rb0.w);
    Bs[bn + 4][bk] = f2b(rb1.x); Bs[bn + 5][bk] = f2b(rb1.y);
    Bs[bn + 6][bk] = f2b(rb1.z); Bs[bn + 7][bk] = f2b(rb1.w);
    if (kc + 1 < KCH / 32) {
      int kb = kb0 + (kc + 1) * 32;
      const u16* ap = &feat[(size_t)(m0 + arow) * cD + kb + ak];
      ra0 = *(const uint4*)ap; ra1 = *(const uint4*)(ap + 8);
      const float* bp = &W1[(size_t)(kb + bk) * cDH + n0 + bn];
      rb0 = *(const float4*)bp; rb1 = *(const float4*)(bp + 4);
    }
    __syncthreads();
    short8 a[2], bfr[4];
    #pragma unroll
    for (int mt = 0; mt < 2; ++mt) a[mt] = *(const short8*)&As[w * 32 + mt * 16 + r][q * 8];
    #pragma unroll
    for (int nt = 0; nt < 4; ++nt) bfr[nt] = *(const short8*)&Bs[nt * 16 + r][q * 8];
    #pragma unroll
    for (int mt = 0; mt < 2; ++mt)
      #pragma unroll
      for (int nt = 0; nt < 4; ++nt)
        acc[mt][nt] = __builtin_amdgcn_mfma_f32_16x16x32_bf16(a[mt], bfr[nt], acc[mt][nt], 0, 0, 0);
  }
  float* Cp = Cpart + (size_t)blockIdx.y * 256 * cDH;
  #pragma unroll
  for (int mt = 0; mt < 2; ++mt) {
    #pragma unroll
    for (int nt = 0; nt < 4; ++nt) {
      #pragma unroll
      for (int rg = 0; rg < 4; ++rg) {
        int row = m0 + w * 32 + mt * 16 + q * 4 + rg;
        int col = n0 + nt * 16 + r;
        Cp[(size_t)row * cDH + col] = acc[mt][nt][rg];
      }
    }
  }
}

// ================= K7: reduce split-K + bias + relu -> hmid (f32) ===========
__global__ void k_bias_relu(const float* __restrict__ Cpart, const float* __restrict__ b1,
                            float* __restrict__ hmid) {
  int i = blockIdx.x * 256 + threadIdx.x;
  float v = b1[i & (cDH - 1)];
  #pragma unroll
  for (int s = 0; s < SPLITS; ++s) v += Cpart[(size_t)s * 256 * cDH + i];
  hmid[i] = fmaxf(v, 0.0f);
}

// ================= K8: heads rreg/rcls =================
__global__ void k_gemm2(const float* __restrict__ hmid, const float* __restrict__ Wr, const float* __restrict__ br,
                        const float* __restrict__ Wc, const float* __restrict__ bc,
                        float* __restrict__ rreg, float* __restrict__ rcls) {
  int w = threadIdx.x >> 6, lane = threadIdx.x & 63;
  int row = blockIdx.x * 4 + w;
  float part[25];
  #pragma unroll
  for (int c = 0; c < 25; ++c) part[c] = 0.0f;
  for (int k = lane; k < cDH; k += 64) {
    float h = hmid[(size_t)row * cDH + k];
    #pragma unroll
    for (int c = 0; c < 4; ++c) part[c] += h * Wr[k * 4 + c];
    #pragma unroll
    for (int c = 0; c < 21; ++c) part[4 + c] += h * Wc[k * 21 + c];
  }
  #pragma unroll
  for (int off = 32; off; off >>= 1) {
    #pragma unroll
    for (int c = 0; c < 25; ++c) part[c] += __shfl_down(part[c], off, 64);
  }
  if (lane == 0) {
    #pragma unroll
    for (int c = 0; c < 4; ++c) rreg[row * 4 + c] = part[c] + br[c];
    #pragma unroll
    for (int c = 0; c < 21; ++c) rcls[row * 21 + c] = part[4 + c] + bc[c];
  }
}

// ================= K9: final losses =================
__global__ void k_final(const float* __restrict__ rcls, const float* __restrict__ rreg,
                        const int* __restrict__ cls_s, const float* __restrict__ tgt,
                        float* __restrict__ out) {
  __shared__ float s_cls, s_acc, s_sl1, s_off;
  int tid = threadIdx.x;
  if (tid == 0) { s_cls = 0.0f; s_acc = 0.0f; s_sl1 = 0.0f; s_off = 0.0f; }
  __syncthreads();
  {
    int row = tid;
    float m = -INFINITY;
    for (int c = 0; c < cNCLS; ++c) m = fmaxf(m, rcls[row * cNCLS + c]);
    float sum = 0.0f;
    for (int c = 0; c < cNCLS; ++c) sum += expf(rcls[row * cNCLS + c] - m);
    float lse = m + logf(sum);
    float closs = lse - rcls[row * cNCLS + cls_s[row]];
    atomicAdd(&s_cls, closs);
  }
  if (tid < 64) {
    int am = 0; float bv = rcls[tid * cNCLS];
    for (int c = 1; c < cNCLS; ++c) {
      float v = rcls[tid * cNCLS + c];
      if (v > bv) { bv = v; am = c; }
    }
    if (am == cls_s[tid]) atomicAdd(&s_acc, 1.0f);
    float sl = 0.0f, of = 0.0f;
    #pragma unroll
    for (int c = 0; c < 4; ++c) {
      float d = fabsf(rreg[tid * 4 + c] - tgt[tid * 4 + c]);
      sl += (d < 1.0f) ? 0.5f * d * d : d - 0.5f;
      of += d;
    }
    atomicAdd(&s_sl1, sl);
    atomicAdd(&s_off, of);
  }
  __syncthreads();
  if (tid == 0) {
    out[2] = s_cls / 256.0f;
    out[3] = s_sl1 / 256.0f;
    out[4] = s_acc / 64.0f;
    out[5] = s_off / 256.0f;
  }
}

// ================= launch =================
extern "C" void kernel_launch(void* const* d_in, const int* in_sizes, int n_in,
                              void* d_out, int out_size, void* d_ws, size_t ws_size,
                              hipStream_t stream) {
  const float* nms_reg = (const float*)d_in[0];
  // d_in[1] (nms_cls) unused by the reference loss
  const float* fm      = (const float*)d_in[2];
  const float* bboxes  = (const float*)d_in[3];
  const int*   classes = (const int*)d_in[4];
  const float* anchors = (const float*)d_in[5];
  const float* rpn_reg = (const float*)d_in[6];
  const float* rpn_cls = (const float*)d_in[7];
  const float* W1      = (const float*)d_in[8];
  const float* b1      = (const float*)d_in[9];
  const float* Wr      = (const float*)d_in[10];
  const float* br      = (const float*)d_in[11];
  const float* Wc      = (const float*)d_in[12];
  const float* bc      = (const float*)d_in[13];
  float* out = (float*)d_out;
  char* ws = (char*)d_ws;

  int*      tidx  = (int*)(ws + O_TIDX);
  u64*      maskw = (u64*)(ws + O_MASKW);
  u16*      fmt   = (u16*)(ws + O_FMT);
  float*    Cpart = (float*)(ws + O_CPART);
  int*      sel   = (int*)(ws + O_SEL);
  int*      clss  = (int*)(ws + O_CLS);
  float*    rois  = (float*)(ws + O_ROIS);
  float*    tgt   = (float*)(ws + O_TGT);
  u16*      feat  = (u16*)(ws + O_FEAT);
  float*    hmid  = (float*)(ws + O_HMID);
  float*    rreg  = (float*)(ws + O_RREG);
  float*    rcls  = (float*)(ws + O_RCLS);
  unsigned* keys  = (unsigned*)(ws + O_KEYS);
  int*      ridxg = (int*)(ws + O_RIDXG);

  // RPN branch
  k_rpn_iou<<<cBA / 256, 256, 0, stream>>>(bboxes, anchors, tidx, maskw);
  k_rpn_sample_loss<<<1, 1024, 0, stream>>>(maskw, tidx, rpn_cls, rpn_reg, bboxes, anchors, out);

  // RCNN sampling (grid IoU + radix select)
  k_rcnn_iou<<<(cBR + 255) / 256, 256, 0, stream>>>(nms_reg, bboxes, keys, ridxg);
  k_rcnn_select<<<1, 1024, 0, stream>>>(keys, ridxg, nms_reg, bboxes, classes, sel, clss, rois, tgt);

  // Features + head
  k_fmt<<<dim3(cH * cW / 32, cC / 32, cB), dim3(32, 32), 0, stream>>>(fm, fmt);
  k_roi_pool<<<dim3(256, cPP), 256, 0, stream>>>(fmt, rois, sel, feat);
  k_gemm1<<<dim3(16, SPLITS, 2), 256, 0, stream>>>(feat, W1, Cpart);
  k_bias_relu<<<(256 * cDH) / 256, 256, 0, stream>>>(Cpart, b1, hmid);
  k_gemm2<<<64, 256, 0, stream>>>(hmid, Wr, br, Wc, bc, rreg, rcls);
  k_final<<<1, 256, 0, stream>>>(rcls, rreg, clss, tgt, out);
}

// Round 7
// 201.029 us; speedup vs baseline: 1.5257x; 1.1264x over previous
//
#include <hip/hip_runtime.h>

typedef unsigned short u16;
typedef unsigned long long u64;

// ---------------- problem constants ----------------
constexpr int cB = 4, cT = 40, cR = 2000, cA = 36864;
constexpr int cH = 64, cW = 64, cC = 256, cPP = 7;
constexpr int cNCLS = 21, cNPOS = 64, cNNEG = 192, cDH = 1024;
constexpr int cD = cPP * cPP * cC;          // 12544
constexpr int cBA = cB * cA;                // 147456
constexpr int cBR = cB * cR;                // 8000
constexpr int NW64 = cBA / 64;              // 2304 mask words
constexpr int SPLITS = 8;                   // k-splits for gemm1
constexpr int KCH = cD / SPLITS;            // 1568 = 49*32
constexpr unsigned POSKEY = 0x007FFFFFu;    // f2key(-inf): marks iou>0.5

// ---------------- ws layout (bytes) ----------------
// Region 0 (0..8.39MB) triple duty, stream-ordered:
//   phase 1: tidx (cBA int) + maskw (2304 u64)   [k_ious -> k_select]
//   phase 2: fmt (B,HW,C) bf16 = 8388608 B        [k_fmt -> k_roi_pool]
//   phase 3: Cpart[8][256][1024] f32 = 8388608 B  [k_gemm1 -> k_heads]
constexpr size_t O_TIDX  = 0;                                   // cBA int
constexpr size_t O_MASKW = (size_t)cBA * 4;                     // 2304 u64
constexpr size_t O_FMT   = 0;
constexpr size_t O_CPART = 0;
constexpr size_t O_PERS  = 8388608;
constexpr size_t O_SEL   = O_PERS;                              // 256 int
constexpr size_t O_CLS   = O_PERS + 1024;                       // 256 int
constexpr size_t O_ROIS  = O_PERS + 2048;                       // 256*4 f32
constexpr size_t O_TGT   = O_PERS + 6144;                       // 64*4 f32
constexpr size_t O_FEAT  = O_PERS + 8192;                       // 256*12544 bf16
constexpr size_t O_RREG  = O_FEAT + (size_t)256 * cD * 2;       // 256*4 f32
constexpr size_t O_RCLS  = O_RREG + 4096;                       // 256*21 f32
constexpr size_t O_KEYS  = O_RCLS + 24576;                      // 8000 u32
constexpr size_t O_RIDXG = O_KEYS + 32000;                      // 8000 int

// ---------------- helpers ----------------
__device__ __forceinline__ float b2f(u16 u) {
  return __uint_as_float(((unsigned)u) << 16);
}
__device__ __forceinline__ u16 f2b(float f) {  // f32 -> bf16 bits (RNE)
  unsigned x = __float_as_uint(f);
  unsigned r = x + 0x7FFFu + ((x >> 16) & 1u);
  return (u16)(r >> 16);
}
__device__ __forceinline__ unsigned f2key(float f) {  // monotonic f32->u32
  unsigned b = __float_as_uint(f);
  return b ^ ((b & 0x80000000u) ? 0xFFFFFFFFu : 0x80000000u);
}

typedef __attribute__((ext_vector_type(8))) short short8;
typedef __attribute__((ext_vector_type(4))) float f32x4;

// ================= K1: fused RPN IoU + RCNN IoU =============================
__global__ void k_ious(const float* __restrict__ bboxes, const float* __restrict__ anchors,
                       const float* __restrict__ nms_reg,
                       int* __restrict__ tidx, u64* __restrict__ maskw,
                       unsigned* __restrict__ keys, int* __restrict__ ridxg) {
  __shared__ float sb[cB * cT * 4];
  if (blockIdx.x < 576) {
    // ---- RPN: per (b,a) vs 40 boxes of batch b ----
    int b = blockIdx.x / 144;
    if (threadIdx.x < cT * 4) sb[threadIdx.x] = bboxes[b * cT * 4 + threadIdx.x];
    __syncthreads();
    int i = blockIdx.x * 256 + threadIdx.x;
    int a = i - b * cA;
    float4 av = ((const float4*)anchors)[a];
    float at = av.x, al = av.y, ab = av.z, ar = av.w;
    float area_a = (ab - at) * (ar - al);
    float best = -1.0f; int bi = 0;
    for (int t = 0; t < cT; ++t) {
      float bt = sb[t * 4], bl = sb[t * 4 + 1], bbv = sb[t * 4 + 2], brv = sb[t * 4 + 3];
      float ih = fmaxf(fminf(bbv, ab) - fmaxf(bt, at), 0.0f);
      float iw = fmaxf(fminf(brv, ar) - fmaxf(bl, al), 0.0f);
      float inter = ih * iw;
      float a1 = (bbv - bt) * (brv - bl);
      float iou = inter / (a1 + area_a - inter);
      if (iou > best) { best = iou; bi = t; }
    }
    tidx[i] = bi;
    u64 bal = __ballot(best > 0.5f);
    if ((threadIdx.x & 63) == 0) maskw[i >> 6] = bal;
  } else {
    // ---- RCNN: per (b,r) roi vs its batch's 40 boxes ----
    for (int j = threadIdx.x; j < cB * cT * 4; j += 256) sb[j] = bboxes[j];
    __syncthreads();
    int i = (blockIdx.x - 576) * 256 + threadIdx.x;
    if (i >= cBR) return;
    int b = i / cR;
    float4 nv = ((const float4*)nms_reg)[i];
    float nt = nv.x, nl = nv.y, nb = nv.z, nr = nv.w;
    float area_n = (nb - nt) * (nr - nl);
    float best = -1.0f; int bi = 0;
    for (int t = 0; t < cT; ++t) {
      const float* bx = &sb[(b * cT + t) * 4];
      float ih = fmaxf(fminf(bx[2], nb) - fmaxf(bx[0], nt), 0.0f);
      float iw = fmaxf(fminf(bx[3], nr) - fmaxf(bx[1], nl), 0.0f);
      float inter = ih * iw;
      float a1 = (bx[2] - bx[0]) * (bx[3] - bx[1]);
      float iou = inter / (a1 + area_n - inter);
      if (iou > best) { best = iou; bi = t; }
    }
    keys[i] = (best <= 0.5f) ? f2key(best) : POSKEY;
    ridxg[i] = bi;
  }
}

// ================= K2: fused selection (block 0: RPN, block 1: RCNN) ========
__global__ __launch_bounds__(1024) void k_select(
    const u64* __restrict__ maskw, const int* __restrict__ tidx,
    const float* __restrict__ rpn_cls, const float* __restrict__ rpn_reg,
    const float* __restrict__ bboxes, const float* __restrict__ anchors,
    const unsigned* __restrict__ keysg, const int* __restrict__ ridxg,
    const float* __restrict__ nms_reg, const int* __restrict__ classes,
    int* __restrict__ sel, int* __restrict__ cls_s,
    float* __restrict__ rois, float* __restrict__ tgt,
    float* __restrict__ out) {
  __shared__ __align__(16) char smem[50688];
  __shared__ float s_scalF[2];
  __shared__ int s_scalI[3];
  int tid = threadIdx.x, lane = tid & 63, w = tid >> 6;
  u64 lmask = (1ULL << lane) - 1ULL;

  if (blockIdx.x == 0) {
    // ================== RPN sample + losses ==================
    u64* s_w   = (u64*)smem;                 // 2304*8 = 18432
    int* s_pre = (int*)(smem + 18432);       // 144
    int* s_cw  = (int*)(smem + 19008);       // 144
    int* s_pos = (int*)(smem + 19584);       // 128
    int* s_neg = (int*)(smem + 20096);       // 252
    for (int k = tid; k < NW64; k += 1024) s_w[k] = maskw[k];
    if (tid < 128) s_pos[tid] = 0;
    if (tid < 252) s_neg[tid] = 0;
    if (tid == 0) { s_scalF[0] = 0.0f; s_scalF[1] = 0.0f; }
    __syncthreads();
    if (tid < 144) {
      int c = 0;
      #pragma unroll
      for (int k2 = 0; k2 < 16; ++k2) c += __popcll(s_w[tid * 16 + k2]);
      s_cw[tid] = c;
    }
    __syncthreads();
    if (tid == 0) {
      int run = 0;
      for (int ch = 0; ch < 144; ++ch) { s_pre[ch] = run; run += s_cw[ch]; }
    }
    __syncthreads();
    for (int ch = w; ch < 144; ch += 16) {
      int pbase = s_pre[ch];
      int nbase = ch * 1024 - pbase;
      if (pbase >= 128 && nbase >= 252) continue;
      int pc = 0;
      #pragma unroll
      for (int s2 = 0; s2 < 16; ++s2) {
        u64 word = s_w[ch * 16 + s2];
        bool m = (word >> lane) & 1ULL;
        int prefP = __popcll(word & lmask);
        int idx = ch * 1024 + s2 * 64 + lane;
        if (m) {
          int g = pbase + pc + prefP;
          if (g < 128) s_pos[g] = idx;
        } else {
          int g = nbase + (s2 * 64 + lane) - (pc + prefP);
          if (g < 252) s_neg[g] = idx;
        }
        pc += __popcll(word);
      }
    }
    __syncthreads();
    if (tid < 380) {
      int flat; float lbl;
      if (tid < 128) { flat = s_pos[tid]; lbl = 1.0f; }
      else           { flat = s_neg[tid - 128]; lbl = 0.0f; }
      float l = rpn_cls[flat];
      float term = fmaxf(l, 0.0f) - l * lbl + log1pf(expf(-fabsf(l)));
      atomicAdd(&s_scalF[0], term);
    }
    if (tid < 512) {
      int j = tid >> 2, c = tid & 3;
      int flat = s_pos[j];
      int b = flat / cA, a = flat - b * cA;
      int t = tidx[flat];
      float p = rpn_reg[flat * 4 + c];
      float tg = bboxes[(b * cT + t) * 4 + c] - anchors[a * 4 + c];
      float d = fabsf(p - tg);
      float sl = (d < 1.0f) ? 0.5f * d * d : d - 0.5f;
      atomicAdd(&s_scalF[1], sl);
    }
    __syncthreads();
    if (tid == 0) {
      out[0] = s_scalF[0] / 380.0f;
      out[1] = s_scalF[1] / 512.0f / 4.0f;
    }
  } else {
    // ================== RCNN radix select ==================
    unsigned* s_key = (unsigned*)smem;           // 32000
    int* s_hist = (int*)(smem + 32000);          // 16384
    int* s_pc   = (int*)(smem + 48384);          // 512
    int* s_wsum = (int*)(smem + 48896);          // 64
    int* s_wsuf = (int*)(smem + 48960);          // 64
    int* s_posr = (int*)(smem + 49024);          // 256
    int* s_negr = (int*)(smem + 49280);          // 768

    for (int i = tid; i < cBR; i += 1024) s_key[i] = keysg[i];
    if (tid < 64) s_posr[tid] = 0;
    __syncthreads();

    // posr: first 64 with key==POSKEY (2-barrier rank fill)
    {
      int myv = 0; int mypre[8];
      #pragma unroll
      for (int p = 0; p < 8; ++p) {
        int i = p * 1024 + tid;
        bool v = (i < cBR) && (s_key[i] == POSKEY);
        u64 bal = __ballot(v);
        if (lane == 0) s_pc[p * 16 + w] = __popcll(bal);
        mypre[p] = __popcll(bal & lmask);
        myv |= v ? (1 << p) : 0;
      }
      __syncthreads();
      if (tid == 0) {
        int run = 0;
        for (int k = 0; k < 128; ++k) { int t = s_pc[k]; s_pc[k] = run; run += t; }
      }
      __syncthreads();
      #pragma unroll
      for (int p = 0; p < 8; ++p) {
        if (myv & (1 << p)) {
          int g = s_pc[p * 16 + w] + mypre[p];
          if (g < 64) s_posr[g] = p * 1024 + tid;
        }
      }
    }

    // 3-level radix threshold: exact 192nd-largest key
    unsigned thr = 0; int G = 0;
    int need = cNNEG;
    #pragma unroll
    for (int lvl = 0; lvl < 3; ++lvl) {
      __syncthreads();
      #pragma unroll
      for (int k = 0; k < 4; ++k) s_hist[tid * 4 + k] = 0;
      __syncthreads();
      #pragma unroll
      for (int p = 0; p < 8; ++p) {
        int i = p * 1024 + tid;
        if (i < cBR) {
          unsigned key = s_key[i];
          int bkt = -1;
          if (lvl == 0) bkt = key >> 20;
          else if (lvl == 1) { if ((key >> 20) == (thr >> 20)) bkt = (key >> 8) & 0xFFF; }
          else { if ((key >> 8) == (thr >> 8)) bkt = (key & 0xFF) << 4; }
          if (bkt >= 0) atomicAdd(&s_hist[bkt], 1);
        }
      }
      __syncthreads();
      int local0 = s_hist[tid * 4 + 0], local1 = s_hist[tid * 4 + 1];
      int local2 = s_hist[tid * 4 + 2], local3 = s_hist[tid * 4 + 3];
      int lsum = local0 + local1 + local2 + local3;
      int x = lsum;
      #pragma unroll
      for (int off = 1; off < 64; off <<= 1) {
        int t = __shfl_down(x, off, 64);
        if (lane + off < 64) x += t;
      }
      if (lane == 0) s_wsum[w] = x;
      __syncthreads();
      if (tid == 0) {
        int run = 0;
        for (int wi = 15; wi >= 0; --wi) { s_wsuf[wi] = run; run += s_wsum[wi]; }
      }
      __syncthreads();
      int above = s_wsuf[w] + (x - lsum);
      int run = above;
      int loc[4] = {local3, local2, local1, local0};
      #pragma unroll
      for (int j = 0; j < 4; ++j) {
        int S = run + loc[j];
        if (run < need && S >= need) { s_scalI[0] = tid * 4 + (3 - j); s_scalI[1] = run; }
        run = S;
      }
      __syncthreads();
      int bS = s_scalI[0], ov = s_scalI[1];
      if (lvl == 0) thr = ((unsigned)bS) << 20;
      else if (lvl == 1) thr |= ((unsigned)bS) << 8;
      else thr |= ((unsigned)bS) >> 4;
      G += ov;
      need -= ov;
    }

    // negr: unordered strictly-greater, then ties ascending
    if (tid == 0) s_scalI[2] = 0;
    __syncthreads();
    #pragma unroll
    for (int p = 0; p < 8; ++p) {
      int i = p * 1024 + tid;
      if (i < cBR && s_key[i] > thr) {
        int slot = atomicAdd(&s_scalI[2], 1);
        s_negr[slot] = i;
      }
    }
    {
      __syncthreads();
      int myv = 0; int mypre[8];
      #pragma unroll
      for (int p = 0; p < 8; ++p) {
        int i = p * 1024 + tid;
        bool v = (i < cBR) && (s_key[i] == thr);
        u64 bal = __ballot(v);
        if (lane == 0) s_pc[p * 16 + w] = __popcll(bal);
        mypre[p] = __popcll(bal & lmask);
        myv |= v ? (1 << p) : 0;
      }
      __syncthreads();
      if (tid == 0) {
        int run = 0;
        for (int k = 0; k < 128; ++k) { int t = s_pc[k]; s_pc[k] = run; run += t; }
      }
      __syncthreads();
      #pragma unroll
      for (int p = 0; p < 8; ++p) {
        if (myv & (1 << p)) {
          int g = s_pc[p * 16 + w] + mypre[p];
          if (g < need) s_negr[G + g] = p * 1024 + tid;
        }
      }
    }
    __syncthreads();

    if (tid < 256) {
      int flat = (tid < 64) ? s_posr[tid] : s_negr[tid - 64];
      sel[tid] = flat;
      int b = flat / cR;
      #pragma unroll
      for (int c = 0; c < 4; ++c) rois[tid * 4 + c] = nms_reg[flat * 4 + c];
      cls_s[tid] = (tid < 64) ? classes[b * cT + ridxg[flat]] : 0;
      if (tid < 64) {
        int mt = ridxg[flat];
        #pragma unroll
        for (int c = 0; c < 4; ++c) {
          float v = nms_reg[flat * 4 + c];
          float rr = ((c < 2) ? floorf(v * 16.0f) : ceilf(v * 16.0f)) / 16.0f;
          float mbv = bboxes[(b * cT + mt) * 4 + c];
          tgt[tid * 4 + c] = mbv - rr;
        }
      }
    }
  }
}

// ================= K3: transpose fm (B,C,HW) f32 -> fmt (B,HW,C) bf16 =======
// float4 loads (256B/16-lane), bf16-pair packed uint4 stores (16B/lane).
__global__ __launch_bounds__(256) void k_fmt(const float* __restrict__ fm, u16* __restrict__ fmt) {
  __shared__ float tile[64][65];
  int b = blockIdx.z;
  int p0 = blockIdx.x * 64, c0 = blockIdx.y * 64;
  int t = threadIdx.x;
  int pL = (t & 15) * 4, cL = t >> 4;
  #pragma unroll
  for (int i = 0; i < 4; ++i) {
    int c = cL + i * 16;
    float4 v = *(const float4*)&fm[((size_t)b * cC + c0 + c) * (cH * cW) + p0 + pL];
    tile[c][pL] = v.x; tile[c][pL + 1] = v.y; tile[c][pL + 2] = v.z; tile[c][pL + 3] = v.w;
  }
  __syncthreads();
  int pW = t >> 2, cg = (t & 3) * 16;
  unsigned pk[8];
  #pragma unroll
  for (int j = 0; j < 8; ++j) {
    unsigned lo = f2b(tile[cg + 2 * j][pW]);
    unsigned hi = f2b(tile[cg + 2 * j + 1][pW]);
    pk[j] = lo | (hi << 16);
  }
  u16* dst = &fmt[((size_t)b * (cH * cW) + p0 + pW) * cC + c0 + cg];
  *(uint4*)dst = *(uint4*)&pk[0];
  *(uint4*)(dst + 8) = *(uint4*)&pk[4];
}

// ================= K4: ROI align (coalesced, one block per roi x bin-row) ===
__global__ void k_roi_pool(const u16* __restrict__ fmt, const float* __restrict__ rois,
                           const int* __restrict__ sel, u16* __restrict__ feat) {
  int j = blockIdx.x;    // roi
  int py = blockIdx.y;   // bin row 0..6
  int c = threadIdx.x;   // channel
  int flat = sel[j];
  int n = flat / cR;
  float t = rois[j * 4 + 0], l = rois[j * 4 + 1];
  float bb = rois[j * 4 + 2], r = rois[j * 4 + 3];
  const u16* base = fmt + (size_t)n * (cH * cW) * cC;
  float gy = (py + 0.5f) / (float)cPP;
  float ys = fminf(fmaxf(t + gy * (bb - t), 0.0f), 63.0f);
  int y0 = (int)floorf(ys);
  int y1 = min(y0 + 1, 63);
  float wy = ys - (float)y0;
  #pragma unroll
  for (int px = 0; px < cPP; ++px) {
    float gx = (px + 0.5f) / (float)cPP;
    float xs = fminf(fmaxf(l + gx * (r - l), 0.0f), 63.0f);
    int x0 = (int)floorf(xs);
    int x1 = min(x0 + 1, 63);
    float wx = xs - (float)x0;
    float f00 = b2f(base[(y0 * cW + x0) * cC + c]);
    float f01 = b2f(base[(y0 * cW + x1) * cC + c]);
    float f10 = b2f(base[(y1 * cW + x0) * cC + c]);
    float f11 = b2f(base[(y1 * cW + x1) * cC + c]);
    float v = f00 * (1.0f - wy) * (1.0f - wx) + f01 * (1.0f - wy) * wx +
              f10 * wy * (1.0f - wx) + f11 * wy * wx;
    feat[((size_t)j * 49 + py * cPP + px) * cC + c] = f2b(v);
  }
}

// ================= K5: GEMM1 feat(256x12544 bf16) @ W1(12544x1024 f32) ======
// Grid (16 n, 8 ksplit, 4 m) = 512 blocks = 2/CU. M=64, N=64, K=1568.
// B-staging XOR-swizzled by (row>>3)&3 to kill 8-way write conflicts.
__global__ __launch_bounds__(256) void k_gemm1(const u16* __restrict__ feat, const float* __restrict__ W1,
                                               float* __restrict__ Cpart) {
  __shared__ u16 As[64][56];
  __shared__ u16 Bs[64][56];
  int tid = threadIdx.x;
  int n0 = blockIdx.x * 64;
  int kb0 = blockIdx.y * KCH;
  int m0 = blockIdx.z * 64;
  int lane = tid & 63, w = tid >> 6;
  int r = lane & 15, q = lane >> 4;
  f32x4 acc[4] = {};
  int arow = tid >> 2, ak = (tid & 3) * 8;      // A: 64 rows x 32 k, one uint4/thread
  int bk = tid >> 3, bn = (tid & 7) * 8;        // B: 32 k x 64 n, 8 f32/thread
  uint4 ra;
  float4 rb0, rb1;
  {
    ra = *(const uint4*)&feat[(size_t)(m0 + arow) * cD + kb0 + ak];
    const float* bp = &W1[(size_t)(kb0 + bk) * cDH + n0 + bn];
    rb0 = *(const float4*)bp; rb1 = *(const float4*)(bp + 4);
  }
  for (int kc = 0; kc < KCH / 32; ++kc) {
    __syncthreads();
    *(uint4*)&As[arow][ak] = ra;
    {
      float bv[8] = {rb0.x, rb0.y, rb0.z, rb0.w, rb1.x, rb1.y, rb1.z, rb1.w};
      int kg = bk >> 3, kw = bk & 7;
      #pragma unroll
      for (int i = 0; i < 8; ++i) {
        int row = bn + i;
        Bs[row][((kg ^ ((row >> 3) & 3)) << 3) + kw] = f2b(bv[i]);
      }
    }
    if (kc + 1 < KCH / 32) {
      int kb = kb0 + (kc + 1) * 32;
      ra = *(const uint4*)&feat[(size_t)(m0 + arow) * cD + kb + ak];
      const float* bp = &W1[(size_t)(kb + bk) * cDH + n0 + bn];
      rb0 = *(const float4*)bp; rb1 = *(const float4*)(bp + 4);
    }
    __syncthreads();
    short8 a = *(const short8*)&As[w * 16 + r][q * 8];
    #pragma unroll
    for (int nt = 0; nt < 4; ++nt) {
      int n = nt * 16 + r;
      short8 bfr = *(const short8*)&Bs[n][(q ^ ((n >> 3) & 3)) << 3];
      acc[nt] = __builtin_amdgcn_mfma_f32_16x16x32_bf16(a, bfr, acc[nt], 0, 0, 0);
    }
  }
  float* Cp = Cpart + (size_t)blockIdx.y * 256 * cDH;
  #pragma unroll
  for (int nt = 0; nt < 4; ++nt) {
    #pragma unroll
    for (int rg = 0; rg < 4; ++rg) {
      int row = m0 + w * 16 + q * 4 + rg;
      int col = n0 + nt * 16 + r;
      Cp[(size_t)row * cDH + col] = acc[nt][rg];
    }
  }
}

// ================= K6: heads (split-K reduce + bias + relu + gemm2) =========
__global__ void k_heads(const float* __restrict__ Cpart, const float* __restrict__ b1,
                        const float* __restrict__ Wr, const float* __restrict__ br,
                        const float* __restrict__ Wc, const float* __restrict__ bc,
                        float* __restrict__ rreg, float* __restrict__ rcls) {
  int w = threadIdx.x >> 6, lane = threadIdx.x & 63;
  int row = blockIdx.x * 4 + w;
  float part[25];
  #pragma unroll
  for (int c = 0; c < 25; ++c) part[c] = 0.0f;
  for (int k = lane; k < cDH; k += 64) {
    float h = b1[k];
    #pragma unroll
    for (int s = 0; s < SPLITS; ++s) h += Cpart[(size_t)s * 256 * cDH + (size_t)row * cDH + k];
    h = fmaxf(h, 0.0f);
    #pragma unroll
    for (int c = 0; c < 4; ++c) part[c] += h * Wr[k * 4 + c];
    #pragma unroll
    for (int c = 0; c < 21; ++c) part[4 + c] += h * Wc[k * 21 + c];
  }
  #pragma unroll
  for (int off = 32; off; off >>= 1) {
    #pragma unroll
    for (int c = 0; c < 25; ++c) part[c] += __shfl_down(part[c], off, 64);
  }
  if (lane == 0) {
    #pragma unroll
    for (int c = 0; c < 4; ++c) rreg[row * 4 + c] = part[c] + br[c];
    #pragma unroll
    for (int c = 0; c < 21; ++c) rcls[row * 21 + c] = part[4 + c] + bc[c];
  }
}

// ================= K7: final losses =================
__global__ void k_final(const float* __restrict__ rcls, const float* __restrict__ rreg,
                        const int* __restrict__ cls_s, const float* __restrict__ tgt,
                        float* __restrict__ out) {
  __shared__ float s_cls, s_acc, s_sl1, s_off;
  int tid = threadIdx.x;
  if (tid == 0) { s_cls = 0.0f; s_acc = 0.0f; s_sl1 = 0.0f; s_off = 0.0f; }
  __syncthreads();
  {
    int row = tid;
    float m = -INFINITY;
    for (int c = 0; c < cNCLS; ++c) m = fmaxf(m, rcls[row * cNCLS + c]);
    float sum = 0.0f;
    for (int c = 0; c < cNCLS; ++c) sum += expf(rcls[row * cNCLS + c] - m);
    float lse = m + logf(sum);
    float closs = lse - rcls[row * cNCLS + cls_s[row]];
    atomicAdd(&s_cls, closs);
  }
  if (tid < 64) {
    int am = 0; float bv = rcls[tid * cNCLS];
    for (int c = 1; c < cNCLS; ++c) {
      float v = rcls[tid * cNCLS + c];
      if (v > bv) { bv = v; am = c; }
    }
    if (am == cls_s[tid]) atomicAdd(&s_acc, 1.0f);
    float sl = 0.0f, of = 0.0f;
    #pragma unroll
    for (int c = 0; c < 4; ++c) {
      float d = fabsf(rreg[tid * 4 + c] - tgt[tid * 4 + c]);
      sl += (d < 1.0f) ? 0.5f * d * d : d - 0.5f;
      of += d;
    }
    atomicAdd(&s_sl1, sl);
    atomicAdd(&s_off, of);
  }
  __syncthreads();
  if (tid == 0) {
    out[2] = s_cls / 256.0f;
    out[3] = s_sl1 / 256.0f;
    out[4] = s_acc / 64.0f;
    out[5] = s_off / 256.0f;
  }
}

// ================= launch =================
extern "C" void kernel_launch(void* const* d_in, const int* in_sizes, int n_in,
                              void* d_out, int out_size, void* d_ws, size_t ws_size,
                              hipStream_t stream) {
  const float* nms_reg = (const float*)d_in[0];
  // d_in[1] (nms_cls) unused by the reference loss
  const float* fm      = (const float*)d_in[2];
  const float* bboxes  = (const float*)d_in[3];
  const int*   classes = (const int*)d_in[4];
  const float* anchors = (const float*)d_in[5];
  const float* rpn_reg = (const float*)d_in[6];
  const float* rpn_cls = (const float*)d_in[7];
  const float* W1      = (const float*)d_in[8];
  const float* b1      = (const float*)d_in[9];
  const float* Wr      = (const float*)d_in[10];
  const float* br      = (const float*)d_in[11];
  const float* Wc      = (const float*)d_in[12];
  const float* bc      = (const float*)d_in[13];
  float* out = (float*)d_out;
  char* ws = (char*)d_ws;

  int*      tidx  = (int*)(ws + O_TIDX);
  u64*      maskw = (u64*)(ws + O_MASKW);
  u16*      fmt   = (u16*)(ws + O_FMT);
  float*    Cpart = (float*)(ws + O_CPART);
  int*      sel   = (int*)(ws + O_SEL);
  int*      clss  = (int*)(ws + O_CLS);
  float*    rois  = (float*)(ws + O_ROIS);
  float*    tgt   = (float*)(ws + O_TGT);
  u16*      feat  = (u16*)(ws + O_FEAT);
  float*    rreg  = (float*)(ws + O_RREG);
  float*    rcls  = (float*)(ws + O_RCLS);
  unsigned* keys  = (unsigned*)(ws + O_KEYS);
  int*      ridxg = (int*)(ws + O_RIDXG);

  k_ious<<<576 + 32, 256, 0, stream>>>(bboxes, anchors, nms_reg, tidx, maskw, keys, ridxg);
  k_select<<<2, 1024, 0, stream>>>(maskw, tidx, rpn_cls, rpn_reg, bboxes, anchors,
                                   keys, ridxg, nms_reg, classes, sel, clss, rois, tgt, out);
  k_fmt<<<dim3(cH * cW / 64, cC / 64, cB), 256, 0, stream>>>(fm, fmt);
  k_roi_pool<<<dim3(256, cPP), 256, 0, stream>>>(fmt, rois, sel, feat);
  k_gemm1<<<dim3(16, SPLITS, 4), 256, 0, stream>>>(feat, W1, Cpart);
  k_heads<<<64, 256, 0, stream>>>(Cpart, b1, Wr, br, Wc, bc, rreg, rcls);
  k_final<<<1, 256, 0, stream>>>(rcls, rreg, clss, tgt, out);
}